// Round 5
// baseline (355.730 us; speedup 1.0000x reference)
//
#include <hip/hip_runtime.h>
#include <hip/hip_bf16.h>

#define NEG_SLOPE 0.2f

// ---------------------------------------------------------------------------
// Tiled f32 GEMM: D[V,128] = act(A[V,128] @ W[128,128] + bias), optional lrelu
// ---------------------------------------------------------------------------
__global__ __launch_bounds__(256) void gemm128(const float* __restrict__ A,
                                               const float* __restrict__ W,
                                               const float* __restrict__ bias,
                                               float* __restrict__ D,
                                               int V, int lrelu)
{
    __shared__ float As[32][65];    // transposed [k][row], padded
    __shared__ float Bs[32][128];   // [k][col]
    const int tid = threadIdx.x;
    const int tx = tid & 15;
    const int ty = tid >> 4;
    const int row0 = blockIdx.x * 64;

    float acc[4][8];
#pragma unroll
    for (int i = 0; i < 4; ++i)
#pragma unroll
        for (int j = 0; j < 8; ++j) acc[i][j] = 0.f;

    for (int k0 = 0; k0 < 128; k0 += 32) {
        {
            const int c = (tid & 7) * 4;
#pragma unroll
            for (int p = 0; p < 2; ++p) {
                const int r = (tid >> 3) + 32 * p;
                const int gr = row0 + r;
                float4 a = make_float4(0.f, 0.f, 0.f, 0.f);
                if (gr < V) a = *(const float4*)(A + (size_t)gr * 128 + k0 + c);
                As[c + 0][r] = a.x; As[c + 1][r] = a.y;
                As[c + 2][r] = a.z; As[c + 3][r] = a.w;
            }
        }
        {
            const int r = tid >> 5;
            const int c = (tid & 31) * 4;
#pragma unroll
            for (int p = 0; p < 4; ++p) {
                float4 b = *(const float4*)(W + (size_t)(k0 + r + 8 * p) * 128 + c);
                *(float4*)&Bs[r + 8 * p][c] = b;
            }
        }
        __syncthreads();
#pragma unroll 8
        for (int kk = 0; kk < 32; ++kk) {
            float a[4];
#pragma unroll
            for (int i = 0; i < 4; ++i) a[i] = As[kk][ty * 4 + i];
            const float4 b0 = *(const float4*)&Bs[kk][tx * 8];
            const float4 b1 = *(const float4*)&Bs[kk][tx * 8 + 4];
            const float b[8] = {b0.x, b0.y, b0.z, b0.w, b1.x, b1.y, b1.z, b1.w};
#pragma unroll
            for (int i = 0; i < 4; ++i)
#pragma unroll
                for (int j = 0; j < 8; ++j) acc[i][j] += a[i] * b[j];
        }
        __syncthreads();
    }

#pragma unroll
    for (int i = 0; i < 4; ++i) {
        const int gr = row0 + ty * 4 + i;
        if (gr >= V) continue;
#pragma unroll
        for (int j = 0; j < 8; j += 4) {
            float4 o;
            float* op = &o.x;
#pragma unroll
            for (int jj = 0; jj < 4; ++jj) {
                const int c = tx * 8 + j + jj;
                float x = acc[i][j + jj] + bias[c];
                if (lrelu) x = (x > 0.f) ? x : NEG_SLOPE * x;
                op[jj] = x;
            }
            *(float4*)(D + (size_t)gr * 128 + tx * 8 + j) = o;
        }
    }
}

// ---------------------------------------------------------------------------
// Fused Q/K/V projection: three GEMMs sharing the A-tile staging.
// ---------------------------------------------------------------------------
__global__ __launch_bounds__(256) void gemm_qkv(
    const float* __restrict__ A,
    const float* __restrict__ W0, const float* __restrict__ W1, const float* __restrict__ W2,
    const float* __restrict__ b0, const float* __restrict__ b1, const float* __restrict__ b2,
    float* __restrict__ D0, float* __restrict__ D1, float* __restrict__ D2, int V)
{
    __shared__ float As[32][65];
    __shared__ float Bs[3][32][128];
    const int tid = threadIdx.x;
    const int tx = tid & 15;
    const int ty = tid >> 4;
    const int row0 = blockIdx.x * 64;
    const float* Ws[3] = {W0, W1, W2};
    const float* bs[3] = {b0, b1, b2};
    float* Ds[3] = {D0, D1, D2};

    float acc[3][4][8];
#pragma unroll
    for (int m = 0; m < 3; ++m)
#pragma unroll
        for (int i = 0; i < 4; ++i)
#pragma unroll
            for (int j = 0; j < 8; ++j) acc[m][i][j] = 0.f;

    for (int k0 = 0; k0 < 128; k0 += 32) {
        {
            const int c = (tid & 7) * 4;
#pragma unroll
            for (int p = 0; p < 2; ++p) {
                const int r = (tid >> 3) + 32 * p;
                const int gr = row0 + r;
                float4 a = make_float4(0.f, 0.f, 0.f, 0.f);
                if (gr < V) a = *(const float4*)(A + (size_t)gr * 128 + k0 + c);
                As[c + 0][r] = a.x; As[c + 1][r] = a.y;
                As[c + 2][r] = a.z; As[c + 3][r] = a.w;
            }
        }
        {
            const int r = tid >> 5;
            const int c = (tid & 31) * 4;
#pragma unroll
            for (int m = 0; m < 3; ++m)
#pragma unroll
                for (int p = 0; p < 4; ++p) {
                    float4 b = *(const float4*)(Ws[m] + (size_t)(k0 + r + 8 * p) * 128 + c);
                    *(float4*)&Bs[m][r + 8 * p][c] = b;
                }
        }
        __syncthreads();
#pragma unroll 4
        for (int kk = 0; kk < 32; ++kk) {
            float a[4];
#pragma unroll
            for (int i = 0; i < 4; ++i) a[i] = As[kk][ty * 4 + i];
#pragma unroll
            for (int m = 0; m < 3; ++m) {
                const float4 q0 = *(const float4*)&Bs[m][kk][tx * 8];
                const float4 q1 = *(const float4*)&Bs[m][kk][tx * 8 + 4];
                const float b[8] = {q0.x, q0.y, q0.z, q0.w, q1.x, q1.y, q1.z, q1.w};
#pragma unroll
                for (int i = 0; i < 4; ++i)
#pragma unroll
                    for (int j = 0; j < 8; ++j) acc[m][i][j] += a[i] * b[j];
            }
        }
        __syncthreads();
    }

#pragma unroll
    for (int m = 0; m < 3; ++m)
#pragma unroll
        for (int i = 0; i < 4; ++i) {
            const int gr = row0 + ty * 4 + i;
            if (gr >= V) continue;
#pragma unroll
            for (int j = 0; j < 8; j += 4) {
                float4 o;
                float* op = &o.x;
#pragma unroll
                for (int jj = 0; jj < 4; ++jj)
                    op[jj] = acc[m][i][j + jj] + bs[m][tx * 8 + j + jj];
                *(float4*)(Ds[m] + (size_t)gr * 128 + tx * 8 + j) = o;
            }
        }
}

// ---------------------------------------------------------------------------
// Per-target in-degree count
// ---------------------------------------------------------------------------
__global__ __launch_bounds__(256) void count_tgt(const int* __restrict__ tgt,
                                                 int* __restrict__ cnt, int E)
{
    const int e = blockIdx.x * blockDim.x + threadIdx.x;
    if (e < E) atomicAdd(cnt + tgt[e], 1);
}

// ---------------------------------------------------------------------------
// CSR build: block-wise exclusive scan of per-node counts
// ---------------------------------------------------------------------------
__global__ __launch_bounds__(256) void scan1(const int* __restrict__ cnt,
                                             int* __restrict__ offs,
                                             int* __restrict__ bsums, int V)
{
    __shared__ int sh[256];
    const int t = threadIdx.x;
    const int base = blockIdx.x * 1024;
    int v[4];
    int s = 0;
#pragma unroll
    for (int i = 0; i < 4; ++i) {
        const int idx = base + t * 4 + i;
        v[i] = (idx < V) ? cnt[idx] : 0;
        s += v[i];
    }
    sh[t] = s;
    __syncthreads();
    for (int off = 1; off < 256; off <<= 1) {
        const int x = (t >= off) ? sh[t - off] : 0;
        __syncthreads();
        sh[t] += x;
        __syncthreads();
    }
    int run = (t > 0) ? sh[t - 1] : 0;
#pragma unroll
    for (int i = 0; i < 4; ++i) {
        const int idx = base + t * 4 + i;
        if (idx < V) offs[idx] = run;
        run += v[i];
    }
    if (t == 255) bsums[blockIdx.x] = sh[255];
}

__global__ void scan2(int* __restrict__ bsums, int nb)
{
    if (threadIdx.x == 0 && blockIdx.x == 0) {
        int run = 0;
        for (int i = 0; i < nb; ++i) { const int x = bsums[i]; bsums[i] = run; run += x; }
    }
}

__global__ __launch_bounds__(256) void scan3(int* __restrict__ offs,
                                             const int* __restrict__ bsums,
                                             int* __restrict__ fill, int V)
{
    const int v = blockIdx.x * blockDim.x + threadIdx.x;
    if (v >= V) return;
    const int o = offs[v] + bsums[v >> 10];
    offs[v] = o;
    fill[v] = o;
}

// ---------------------------------------------------------------------------
// Scatter edges into target-sorted order: packed (src, edge weight) int2.
// ---------------------------------------------------------------------------
__global__ __launch_bounds__(256) void scatter_edges(
    const int* __restrict__ src, const int* __restrict__ tgt,
    const float* __restrict__ ew, int* __restrict__ fill,
    int2* __restrict__ se, int E)
{
    const int e = blockIdx.x * blockDim.x + threadIdx.x;
    if (e >= E) return;
    const int pos = atomicAdd(fill + tgt[e], 1);
    se[pos] = make_int2(src[e], __float_as_int(ew[e]));
}

// ---------------------------------------------------------------------------
// Fused per-node kernel: QK^T logits + exp + softmax-denominator + weighted
// Vv aggregation + normalization. One wave per node.
//   Per 16-edge batch: load (src,w); PREFETCH all 16 Vv rows into registers
//   (independent of the dot chain); load Q row into regs; dot vs LDS K;
//   p=exp(...); shfl-broadcast coefs; FMA with prefetched rows.
//   Single latency window per batch instead of two.
// Ksh padded [4][36] per wave: head slices land on banks {0,4,8,12} ->
// conflict-free ds_read_b128 broadcast.
// ---------------------------------------------------------------------------
__global__ __launch_bounds__(256) void fused_agg(
    const float* __restrict__ Q, const float* __restrict__ K,
    const float* __restrict__ Vv, const int2* __restrict__ se,
    const int* __restrict__ offs, const int* __restrict__ fill,
    const float* __restrict__ Wei, const float* __restrict__ bei,
    float* __restrict__ accum, int V)
{
    __shared__ float Ksh[4][4][36];   // [wave][head][32 padded to 36]
    const int wid  = threadIdx.x >> 6;
    const int node = blockIdx.x * 4 + wid;
    if (node >= V) return;
    const int l  = threadIdx.x & 63;
    const int h  = l & 3;    // stage-A head (lane = jj*4 + h)
    const int hd = l >> 4;   // stage-B head (lane owns dims 2l,2l+1)

    // stage K row into padded LDS (wave-local, no barrier needed)
    {
        const float2 kk = *(const float2*)(K + (size_t)node * 128 + l * 2);
        const int f0 = l * 2;
        Ksh[wid][f0 >> 5][f0 & 31] = kk.x;
        Ksh[wid][(f0 + 1) >> 5][(f0 + 1) & 31] = kk.y;
    }

    const float weH = Wei[h], beH = bei[h];
    const int start = offs[node];
    const int end   = fill[node];
    const float2* __restrict__ Vv2 = (const float2*)Vv;

    float degacc = 0.f;
    float ax = 0.f, ay = 0.f;

    for (int b0 = start; b0 < end; b0 += 16) {
        const int nj = min(16, end - b0);
        const int jj = l >> 2;
        int   s = 0;
        float w = 0.f;
        if (jj < nj) {
            const int2 t = se[b0 + jj];
            s = t.x;
            w = __int_as_float(t.y);
        }

        // issue Q-row loads (lanes past nj read row 0 -- hot, harmless)
        const float4* qp = (const float4*)(Q + (size_t)s * 128 + h * 32);
        float4 qv[8];
#pragma unroll
        for (int i = 0; i < 8; ++i) qv[i] = qp[i];

        if (nj == 16) {
            // prefetch all 16 Vv rows (independent of the dot chain)
            float2 v[16];
#pragma unroll
            for (int j = 0; j < 16; ++j) {
                const int sj = __shfl(s, j * 4);
                v[j] = Vv2[(size_t)sj * 64 + l];
            }
            // dot against LDS K
            float dot = 0.f;
#pragma unroll
            for (int i = 0; i < 8; ++i) {
                const float4 k = *(const float4*)&Ksh[wid][h][i * 4];
                dot += qv[i].x * k.x + qv[i].y * k.y + qv[i].z * k.z + qv[i].w * k.w;
            }
            float bb = fmaf(w, weH, beH);
            bb = (bb > 0.f) ? bb : NEG_SLOPE * bb;
            const float p = __expf(fmaf(dot, 0.17677669529663687f, bb));
            degacc += p;
            const float coef = p * w;
#pragma unroll
            for (int j = 0; j < 16; ++j) {
                const float cj = __shfl(coef, j * 4 + hd);
                ax = fmaf(cj, v[j].x, ax);
                ay = fmaf(cj, v[j].y, ay);
            }
        } else {
            float dot = 0.f;
#pragma unroll
            for (int i = 0; i < 8; ++i) {
                const float4 k = *(const float4*)&Ksh[wid][h][i * 4];
                dot += qv[i].x * k.x + qv[i].y * k.y + qv[i].z * k.z + qv[i].w * k.w;
            }
            float bb = fmaf(w, weH, beH);
            bb = (bb > 0.f) ? bb : NEG_SLOPE * bb;
            float p = 0.f;
            if (jj < nj) p = __expf(fmaf(dot, 0.17677669529663687f, bb));
            degacc += p;
            const float coef = p * w;
            for (int j = 0; j < nj; ++j) {
                const float cj = __shfl(coef, j * 4 + hd);
                const int   sj = __shfl(s,    j * 4);
                const float2 v = Vv2[(size_t)sj * 64 + l];
                ax = fmaf(cj, v.x, ax);
                ay = fmaf(cj, v.y, ay);
            }
        }
    }

    // reduce degacc across the 16 lanes sharing head (l&3)
    float d = degacc;
    d += __shfl_xor(d, 4);
    d += __shfl_xor(d, 8);
    d += __shfl_xor(d, 16);
    d += __shfl_xor(d, 32);
    const float deg = __shfl(d, hd);      // lane 'hd' holds head hd's sum
    const float inv = 1.0f / (deg + 1e-16f);

    *(float2*)(accum + (size_t)node * 128 + l * 2) = make_float2(ax * inv, ay * inv);
}

// ---------------------------------------------------------------------------
extern "C" void kernel_launch(void* const* d_in, const int* in_sizes, int n_in,
                              void* d_out, int out_size, void* d_ws, size_t ws_size,
                              hipStream_t stream)
{
    const float* h   = (const float*)d_in[0];
    const int*   ei  = (const int*)  d_in[1];
    const float* ew  = (const float*)d_in[2];
    const float* Wq  = (const float*)d_in[3];
    const float* bq  = (const float*)d_in[4];
    const float* Wk  = (const float*)d_in[5];
    const float* bk  = (const float*)d_in[6];
    const float* Wv  = (const float*)d_in[7];
    const float* bv  = (const float*)d_in[8];
    const float* Wo  = (const float*)d_in[9];
    const float* bo  = (const float*)d_in[10];
    const float* Wei = (const float*)d_in[11];
    const float* bei = (const float*)d_in[12];

    const int V = in_sizes[0] / 128;
    const int E = in_sizes[2];
    const int* src = ei;
    const int* tgt = ei + E;

    // workspace layout
    float* Q     = (float*)d_ws;
    float* Km    = Q  + (size_t)V * 128;
    float* Vm    = Km + (size_t)V * 128;
    float* accum = Vm + (size_t)V * 128;
    int2*  se    = (int2*)(accum + (size_t)V * 128);
    int*   cnt   = (int*)(se + E);
    int*   offs  = cnt  + V;
    int*   fill  = offs + V + 1;
    int*   bsums = fill + V;

    hipMemsetAsync(cnt, 0, (size_t)V * sizeof(int), stream);

    const int gemmGrid = (V + 63) / 64;
    gemm_qkv<<<gemmGrid, 256, 0, stream>>>(h, Wq, Wk, Wv, bq, bk, bv, Q, Km, Vm, V);

    count_tgt<<<(E + 255) / 256, 256, 0, stream>>>(tgt, cnt, E);
    const int nb = (V + 1023) / 1024;
    scan1<<<nb, 256, 0, stream>>>(cnt, offs, bsums, V);
    scan2<<<1, 64, 0, stream>>>(bsums, nb);
    scan3<<<(V + 255) / 256, 256, 0, stream>>>(offs, bsums, fill, V);
    scatter_edges<<<(E + 255) / 256, 256, 0, stream>>>(
        src, tgt, ew, fill, se, E);

    fused_agg<<<(V + 3) / 4, 256, 0, stream>>>(
        Q, Km, Vm, se, offs, fill, Wei, bei, accum, V);

    gemm128<<<gemmGrid, 256, 0, stream>>>(accum, Wo, bo, (float*)d_out, V, 1);
}